// Round 12
// baseline (580.639 us; speedup 1.0000x reference)
//
#include <hip/hip_runtime.h>
#include <hip/hip_cooperative_groups.h>

namespace cg = cooperative_groups;

#define N_NODES 100000
#define NUM_U 50000
#define D 64
#define NUM_E 3200000
#define NB 391                 // ceil(100000/256) buckets of 256 dst nodes
#define PBLK 500               // build blocks (cooperative grid)
#define BT 512                 // build threads per block
#define CHUNK (NUM_E / PBLK)   // 6400 edges per build block
#define CHUNK4 (CHUNK / 4)     // 1600
#define FCAP 8928              // finalize LDS capacity (mean 8192 + 8 sigma)

__device__ __forceinline__ float bf2f(unsigned short u) {
  return __uint_as_float((unsigned)u << 16);
}
__device__ __forceinline__ unsigned short f2bf(float f) {
  unsigned u = __float_as_uint(f);
  u += 0x7FFF + ((u >> 16) & 1);  // RNE
  return (unsigned short)(u >> 16);
}

// ---- micro: M = (W2@W1)^T (row k, col j), c = b1@W2^T, cc = 0.5c+b2 ----
__global__ __launch_bounds__(256) void micro_kernel(
    const float* __restrict__ W1, const float* __restrict__ W2,
    const float* __restrict__ b1, const float* __restrict__ b2,
    float* __restrict__ M, float* __restrict__ c, float* __restrict__ cc) {
  __shared__ float w1[64][65], w2[64][65];
  int t = (int)threadIdx.x;
  for (int i = t; i < 4096; i += 256) { w1[i >> 6][i & 63] = W1[i]; w2[i >> 6][i & 63] = W2[i]; }
  __syncthreads();
  for (int i = t; i < 4096; i += 256) {
    int k = i >> 6, j = i & 63;
    float s = 0.f;
#pragma unroll
    for (int tt = 0; tt < 64; ++tt) s = fmaf(w2[j][tt], w1[tt][k], s);
    M[i] = s;  // M[k][j]
  }
  if (t < 64) {
    float s = 0.f;
#pragma unroll
    for (int tt = 0; tt < 64; ++tt) s = fmaf(b1[tt], w2[t][tt], s);
    c[t] = s;
    cc[t] = 0.5f * s + b2[t];
  }
}

// ---- z = x @ M, stored bf16 ----
__global__ __launch_bounds__(256) void zmm_kernel(
    const float* __restrict__ xu, const float* __restrict__ xi,
    const float* __restrict__ M, unsigned short* __restrict__ z16) {
  __shared__ float Mt[64][65];
  __shared__ float U[64][65];
  int t = (int)threadIdx.x;
  for (int i = t; i < 4096; i += 256) Mt[i & 63][i >> 6] = M[i];
  int lane = t & 63, row = t >> 6;
  int n0 = (int)blockIdx.x * 64;
#pragma unroll
  for (int i = 0; i < 16; ++i) {
    int nl = row + 4 * i, n = n0 + nl;
    if (n < N_NODES) {
      const float* xr = (n < NUM_U) ? (xu + (size_t)n * D) : (xi + (size_t)(n - NUM_U) * D);
      U[nl][lane] = xr[lane];
    }
  }
  __syncthreads();
#pragma unroll
  for (int i = 0; i < 16; ++i) {
    int nl = row + 4 * i, n = n0 + nl;
    if (n >= N_NODES) continue;
    float s = 0.f;
#pragma unroll
    for (int k = 0; k < 64; ++k) s = fmaf(U[nl][k], Mt[lane][k], s);
    z16[(size_t)n * D + lane] = f2bf(s);
  }
}

// ---- fused cooperative CSR build: zero + hist + scan + partition + finalize ----
__global__ __launch_bounds__(BT) void build_kernel(
    const int4* __restrict__ src4, const int4* __restrict__ dst4,
    const float4* __restrict__ w4, int* __restrict__ tot,
    int* __restrict__ bbase, int* __restrict__ gcursor,
    int* __restrict__ rowptr, int2* __restrict__ staging,
    int2* __restrict__ meta) {
  __shared__ int2 ent[FCAP];  // 71.4 KB (p3 uses first CHUNK entries)
  __shared__ int sA[BT], sB[BT], sC[BT], sD[BT];
  cg::grid_group grid = cg::this_grid();
  int t = (int)threadIdx.x, blk = (int)blockIdx.x;

  // Phase Z: zero tot (all blocks write same value - benign)
  for (int i = t; i < NB; i += BT) tot[i] = 0;
  grid.sync();

  // Phase H: per-block bucket histogram -> atomic add to tot
  {
    int* h = sA;
    for (int i = t; i < NB; i += BT) h[i] = 0;
    __syncthreads();
    int base4 = blk * CHUNK4;
    for (int i = t; i < CHUNK4; i += BT) {
      int4 d = dst4[base4 + i];
      atomicAdd(&h[d.x >> 8], 1); atomicAdd(&h[d.y >> 8], 1);
      atomicAdd(&h[d.z >> 8], 1); atomicAdd(&h[d.w >> 8], 1);
    }
    __syncthreads();
    for (int i = t; i < NB; i += BT)
      if (h[i]) atomicAdd(&tot[i], h[i]);
  }
  grid.sync();

  // Phase S: block 0 scans tot -> bbase + gcursor
  if (blk == 0) {
    int* ps = sB;
    int v = (t < NB) ? tot[t] : 0;
    ps[t] = v;
    __syncthreads();
    for (int o = 1; o < BT; o <<= 1) {
      int a = (t >= o) ? ps[t - o] : 0;
      __syncthreads();
      ps[t] += a;
      __syncthreads();
    }
    if (t < NB) { int e = ps[t] - v; bbase[t] = e; gcursor[t] = e; }
    if (t == 0) { bbase[NB] = NUM_E; rowptr[N_NODES] = NUM_E; }
  }
  grid.sync();

  // Phase P: LDS radix-partition per chunk; coalesced run writes;
  // atomic bump run allocation on gcursor
  {
    int* h = sA;
    int* ps = sB;
    int* lst = sC;
    int* og = sD;
    for (int i = t; i < NB; i += BT) h[i] = 0;
    __syncthreads();
    int base4 = blk * CHUNK4;
    for (int i = t; i < CHUNK4; i += BT) {
      int4 d = dst4[base4 + i];
      atomicAdd(&h[d.x >> 8], 1); atomicAdd(&h[d.y >> 8], 1);
      atomicAdd(&h[d.z >> 8], 1); atomicAdd(&h[d.w >> 8], 1);
    }
    __syncthreads();
    int v = (t < NB) ? h[t] : 0;
    ps[t] = v;
    __syncthreads();
    for (int o = 1; o < BT; o <<= 1) {
      int a = (t >= o) ? ps[t - o] : 0;
      __syncthreads();
      ps[t] += a;
      __syncthreads();
    }
    if (t < NB) {
      lst[t] = ps[t] - v;
      og[t] = v ? atomicAdd(&gcursor[t], v) : 0;
    }
    if (t == NB) lst[NB] = CHUNK;  // t==391 < BT
    __syncthreads();
    if (t < NB) h[t] = lst[t];  // reuse as cursor
    __syncthreads();
    for (int i = t; i < CHUNK4; i += BT) {
      int4 s = src4[base4 + i];
      int4 d = dst4[base4 + i];
      float4 w = w4[base4 + i];
      int p;
      p = atomicAdd(&h[d.x >> 8], 1);
      ent[p] = make_int2(s.x | ((d.x & 255) << 17), __float_as_int(w.x));
      p = atomicAdd(&h[d.y >> 8], 1);
      ent[p] = make_int2(s.y | ((d.y & 255) << 17), __float_as_int(w.y));
      p = atomicAdd(&h[d.z >> 8], 1);
      ent[p] = make_int2(s.z | ((d.z & 255) << 17), __float_as_int(w.z));
      p = atomicAdd(&h[d.w >> 8], 1);
      ent[p] = make_int2(s.w | ((d.w & 255) << 17), __float_as_int(w.w));
    }
    __syncthreads();
    for (int i = t; i < CHUNK; i += BT) {
      int lo = 0, hi = NB;  // largest b with lst[b] <= i
      while (hi - lo > 1) { int mid = (lo + hi) >> 1; if (lst[mid] <= i) lo = mid; else hi = mid; }
      staging[og[lo] + (i - lst[lo])] = ent[i];
    }
  }
  grid.sync();

  // Phase F: per-bucket finalize (blocks 0..NB-1), LDS sort + coalesced write
  if (blk < NB) {
    int* hist = sA;
    int* ps = sB;
    int* cur = sC;
    int bs = bbase[blk], be = bbase[blk + 1];
    int cnt = be - bs;
    if (t < 256) hist[t] = 0;
    __syncthreads();
    for (int i = bs + t; i < be; i += BT) atomicAdd(&hist[staging[i].x >> 17], 1);
    __syncthreads();
    int v = (t < 256) ? hist[t] : 0;
    if (t < 256) ps[t] = v;
    __syncthreads();
    for (int o = 1; o < 256; o <<= 1) {
      int a = (t >= o && t < 256) ? ps[t - o] : 0;
      __syncthreads();
      if (t < 256) ps[t] += a;
      __syncthreads();
    }
    int lexcl = (t < 256) ? (ps[t] - v) : 0;
    int n = blk * 256 + t;
    if (t < 256 && n < N_NODES) rowptr[n] = bs + lexcl;
    if (cnt <= FCAP) {
      if (t < 256) cur[t] = lexcl;
      __syncthreads();
      for (int i = bs + t; i < be; i += BT) {
        int2 m = staging[i];
        int p = atomicAdd(&cur[m.x >> 17], 1);
        ent[p] = make_int2(m.x & 0x1FFFF, m.y);
      }
      __syncthreads();
      for (int i = t; i < cnt; i += BT) meta[bs + i] = ent[i];
    } else {  // fallback: scattered global writes (correctness guard)
      if (t < 256) cur[t] = bs + lexcl;
      __syncthreads();
      for (int i = bs + t; i < be; i += BT) {
        int2 m = staging[i];
        int p = atomicAdd(&cur[m.x >> 17], 1);
        meta[p] = make_int2(m.x & 0x1FFFF, m.y);
      }
    }
  }
}

// ---- G: gather (round-10 proven): bf16 operand, scalar metadata, 8-deep ----
template <bool FINAL>
__global__ __launch_bounds__(256) void gather_kernel(
    const int* __restrict__ rowptr, const int2* __restrict__ meta,
    const unsigned short* __restrict__ gsrc, const unsigned short* __restrict__ z16,
    const float* __restrict__ c, const float* __restrict__ cc,
    float* __restrict__ outf, unsigned short* __restrict__ out16) {
  int t = (int)threadIdx.x, lane = t & 63;
  int wid = (int)((blockIdx.x * blockDim.x + t) >> 6);
  int nw = (int)((gridDim.x * blockDim.x) >> 6);
  float cl = FINAL ? c[lane] : 0.f;
  float ccl = FINAL ? cc[lane] : 0.f;

  for (int n = wid; n < N_NODES; n += nw) {
    int lo = __builtin_amdgcn_readfirstlane(rowptr[n]);
    int hi = __builtin_amdgcn_readfirstlane(rowptr[n + 1]);
    float acc0 = 0.f, acc1 = 0.f, wsum = 0.f;
    int j = lo;
    for (; j + 8 <= hi; j += 8) {
      int2 m0 = meta[j + 0], m1 = meta[j + 1], m2 = meta[j + 2], m3 = meta[j + 3];
      int2 m4 = meta[j + 4], m5 = meta[j + 5], m6 = meta[j + 6], m7 = meta[j + 7];
      float v0 = bf2f(gsrc[((size_t)m0.x << 6) + lane]);
      float v1 = bf2f(gsrc[((size_t)m1.x << 6) + lane]);
      float v2 = bf2f(gsrc[((size_t)m2.x << 6) + lane]);
      float v3 = bf2f(gsrc[((size_t)m3.x << 6) + lane]);
      float v4 = bf2f(gsrc[((size_t)m4.x << 6) + lane]);
      float v5 = bf2f(gsrc[((size_t)m5.x << 6) + lane]);
      float v6 = bf2f(gsrc[((size_t)m6.x << 6) + lane]);
      float v7 = bf2f(gsrc[((size_t)m7.x << 6) + lane]);
      acc0 = fmaf(v0, __int_as_float(m0.y), acc0);
      acc1 = fmaf(v1, __int_as_float(m1.y), acc1);
      acc0 = fmaf(v2, __int_as_float(m2.y), acc0);
      acc1 = fmaf(v3, __int_as_float(m3.y), acc1);
      acc0 = fmaf(v4, __int_as_float(m4.y), acc0);
      acc1 = fmaf(v5, __int_as_float(m5.y), acc1);
      acc0 = fmaf(v6, __int_as_float(m6.y), acc0);
      acc1 = fmaf(v7, __int_as_float(m7.y), acc1);
      if (FINAL) {
        float wa = (__int_as_float(m0.y) + __int_as_float(m1.y)) +
                   (__int_as_float(m2.y) + __int_as_float(m3.y));
        float wb = (__int_as_float(m4.y) + __int_as_float(m5.y)) +
                   (__int_as_float(m6.y) + __int_as_float(m7.y));
        wsum += wa + wb;
      }
    }
    for (; j < hi; ++j) {
      int2 m = meta[j];
      acc0 = fmaf(bf2f(gsrc[((size_t)m.x << 6) + lane]), __int_as_float(m.y), acc0);
      if (FINAL) wsum += __int_as_float(m.y);
    }
    float acc = acc0 + acc1;
    size_t o = ((size_t)n << 6) + lane;
    if (FINAL) {
      float t1n = bf2f(gsrc[o]);  // gsrc == t1 here
      float zn = bf2f(z16[o]);
      outf[o] = 0.25f * acc + 0.5f * t1n + 0.25f * zn + 0.5f * wsum * cl + ccl;
    } else {
      out16[o] = f2bf(acc);
    }
  }
}

extern "C" void kernel_launch(void* const* d_in, const int* in_sizes, int n_in,
                              void* d_out, int out_size, void* d_ws, size_t ws_size,
                              hipStream_t stream) {
  const int* edge_index = (const int*)d_in[0];
  const float* w = (const float*)d_in[1];
  const float* user_emb = (const float*)d_in[2];
  const float* item_emb = (const float*)d_in[3];
  const float* W1 = (const float*)d_in[4];
  const float* b1 = (const float*)d_in[5];
  const float* W2 = (const float*)d_in[6];
  const float* b2 = (const float*)d_in[7];
  float* out = (float*)d_out;

  // workspace layout (~64.5 MB)
  unsigned short* z16 = (unsigned short*)d_ws;          // N*D bf16 (12.8 MB)
  int2* staging = (int2*)(z16 + (size_t)N_NODES * D);   // E int2 (25.6 MB)
  unsigned short* t1_16 = (unsigned short*)staging;     // alias: staging dead after build
  int2* meta = staging + NUM_E;                         // E int2 (25.6 MB)
  int* rowptr = (int*)(meta + NUM_E);                   // N+1 (pad 100352)
  int* tot = rowptr + 100352;                           // NB (pad 392)
  int* bbase = tot + 392;                               // NB+1 (pad 392)
  int* gcursor = bbase + 392;                           // NB (pad 392)
  float* Mbuf = (float*)(gcursor + 392);                // 4096
  float* cbuf = Mbuf + 4096;                            // 64
  float* ccbuf = cbuf + 64;                             // 64

  micro_kernel<<<1, 256, 0, stream>>>(W1, W2, b1, b2, Mbuf, cbuf, ccbuf);
  zmm_kernel<<<(N_NODES + 63) / 64, 256, 0, stream>>>(user_emb, item_emb, Mbuf, z16);

  {
    const int4* src4 = (const int4*)edge_index;
    const int4* dst4 = (const int4*)(edge_index + NUM_E);
    const float4* w4 = (const float4*)w;
    void* args[] = {(void*)&src4, (void*)&dst4, (void*)&w4, (void*)&tot,
                    (void*)&bbase, (void*)&gcursor, (void*)&rowptr,
                    (void*)&staging, (void*)&meta};
    hipLaunchCooperativeKernel((const void*)build_kernel, dim3(PBLK), dim3(BT),
                               args, 0, stream);
  }

  // t1 = S @ z   (bf16 store; overwrites dead staging region)
  gather_kernel<false><<<2048, 256, 0, stream>>>(rowptr, meta, z16, z16, cbuf,
                                                 ccbuf, nullptr, t1_16);
  // out = 0.25*S@t1 + 0.5*t1 + 0.25*z + 0.5*dw*c + cc  (f32 output)
  gather_kernel<true><<<2048, 256, 0, stream>>>(rowptr, meta, t1_16, z16, cbuf,
                                                ccbuf, out, nullptr);
}

// Round 13
// 385.302 us; speedup vs baseline: 1.5070x; 1.5070x over previous
//
#include <hip/hip_runtime.h>

#define N_NODES 100000
#define NUM_U 50000
#define D 64
#define NUM_E 3200000
#define NB 391                 // ceil(100000/256) buckets of 256 dst nodes
#define PBLK 500               // partition blocks
#define CHUNK (NUM_E / PBLK)   // 6400 edges per partition block
#define CHUNK4 (CHUNK / 4)     // 1600
#define FCAP 8928              // finalize LDS capacity (mean 8192 + 8 sigma)

__device__ __forceinline__ float bf2f(unsigned short u) {
  return __uint_as_float((unsigned)u << 16);
}
__device__ __forceinline__ unsigned short f2bf(float f) {
  unsigned u = __float_as_uint(f);
  u += 0x7FFF + ((u >> 16) & 1);  // RNE
  return (unsigned short)(u >> 16);
}

// ---- micro: M = (W2@W1)^T (row k, col j), c = b1@W2^T, cc = 0.5c+b2 ----
__global__ __launch_bounds__(256) void micro_kernel(
    const float* __restrict__ W1, const float* __restrict__ W2,
    const float* __restrict__ b1, const float* __restrict__ b2,
    float* __restrict__ M, float* __restrict__ c, float* __restrict__ cc) {
  __shared__ float w1[64][65], w2[64][65];
  int t = (int)threadIdx.x;
  for (int i = t; i < 4096; i += 256) { w1[i >> 6][i & 63] = W1[i]; w2[i >> 6][i & 63] = W2[i]; }
  __syncthreads();
  for (int i = t; i < 4096; i += 256) {
    int k = i >> 6, j = i & 63;
    float s = 0.f;
#pragma unroll
    for (int tt = 0; tt < 64; ++tt) s = fmaf(w2[j][tt], w1[tt][k], s);
    M[i] = s;  // M[k][j]
  }
  if (t < 64) {
    float s = 0.f;
#pragma unroll
    for (int tt = 0; tt < 64; ++tt) s = fmaf(b1[tt], w2[t][tt], s);
    c[t] = s;
    cc[t] = 0.5f * s + b2[t];
  }
}

// ---- z = x @ M, stored bf16 ----
__global__ __launch_bounds__(256) void zmm_kernel(
    const float* __restrict__ xu, const float* __restrict__ xi,
    const float* __restrict__ M, unsigned short* __restrict__ z16) {
  __shared__ float Mt[64][65];
  __shared__ float U[64][65];
  int t = (int)threadIdx.x;
  for (int i = t; i < 4096; i += 256) Mt[i & 63][i >> 6] = M[i];
  int lane = t & 63, row = t >> 6;
  int n0 = (int)blockIdx.x * 64;
#pragma unroll
  for (int i = 0; i < 16; ++i) {
    int nl = row + 4 * i, n = n0 + nl;
    if (n < N_NODES) {
      const float* xr = (n < NUM_U) ? (xu + (size_t)n * D) : (xi + (size_t)(n - NUM_U) * D);
      U[nl][lane] = xr[lane];
    }
  }
  __syncthreads();
#pragma unroll
  for (int i = 0; i < 16; ++i) {
    int nl = row + 4 * i, n = n0 + nl;
    if (n >= N_NODES) continue;
    float s = 0.f;
#pragma unroll
    for (int k = 0; k < 64; ++k) s = fmaf(U[nl][k], Mt[lane][k], s);
    z16[(size_t)n * D + lane] = f2bf(s);
  }
}

// ---- P1: bucket totals only ----
__global__ __launch_bounds__(256) void p1_hist(const int4* __restrict__ dst4,
                                               int* __restrict__ tot) {
  __shared__ int h[NB];
  int t = (int)threadIdx.x, blk = (int)blockIdx.x;
  for (int i = t; i < NB; i += 256) h[i] = 0;
  __syncthreads();
  int base4 = blk * CHUNK4;
  for (int i = t; i < CHUNK4; i += 256) {
    int4 d = dst4[base4 + i];
    atomicAdd(&h[d.x >> 8], 1); atomicAdd(&h[d.y >> 8], 1);
    atomicAdd(&h[d.z >> 8], 1); atomicAdd(&h[d.w >> 8], 1);
  }
  __syncthreads();
  for (int i = t; i < NB; i += 256)
    if (h[i]) atomicAdd(&tot[i], h[i]);
}

// ---- P2: scan bucket totals -> bbase (pristine) + gcursor (bump-allocated) ----
__global__ __launch_bounds__(512) void p2_scan(const int* __restrict__ tot,
                                               int* __restrict__ bbase,
                                               int* __restrict__ gcursor,
                                               int* __restrict__ rowptr) {
  __shared__ int ps[512];
  int t = (int)threadIdx.x;
  int v = (t < NB) ? tot[t] : 0;
  ps[t] = v;
  __syncthreads();
  for (int o = 1; o < 512; o <<= 1) {
    int a = (t >= o) ? ps[t - o] : 0;
    __syncthreads();
    ps[t] += a;
    __syncthreads();
  }
  if (t < NB) { int e = ps[t] - v; bbase[t] = e; gcursor[t] = e; }
  if (t == 0) { bbase[NB] = NUM_E; rowptr[N_NODES] = NUM_E; }
}

// ---- P3: LDS radix-partition per chunk; coalesced run writes; atomic bump
// run allocation on gcursor ----
__global__ __launch_bounds__(512) void p3_part(const int4* __restrict__ src4,
                                               const int4* __restrict__ dst4,
                                               const float4* __restrict__ w4,
                                               int* __restrict__ gcursor,
                                               int2* __restrict__ staging) {
  __shared__ int2 ent[CHUNK];   // 51.2 KB
  __shared__ int h[NB];         // hist -> cursor
  __shared__ int lst[NB + 1];   // local run starts
  __shared__ int og[NB];        // global run bases
  __shared__ int ps[512];
  int t = (int)threadIdx.x, blk = (int)blockIdx.x;
  for (int i = t; i < NB; i += 512) h[i] = 0;
  __syncthreads();
  int base4 = blk * CHUNK4;
  for (int i = t; i < CHUNK4; i += 512) {
    int4 d = dst4[base4 + i];
    atomicAdd(&h[d.x >> 8], 1); atomicAdd(&h[d.y >> 8], 1);
    atomicAdd(&h[d.z >> 8], 1); atomicAdd(&h[d.w >> 8], 1);
  }
  __syncthreads();
  int v = (t < NB) ? h[t] : 0;
  ps[t] = v;
  __syncthreads();
  for (int o = 1; o < 512; o <<= 1) {
    int a = (t >= o) ? ps[t - o] : 0;
    __syncthreads();
    ps[t] += a;
    __syncthreads();
  }
  if (t < NB) {
    lst[t] = ps[t] - v;
    og[t] = v ? atomicAdd(&gcursor[t], v) : 0;
  }
  if (t == 0) lst[NB] = CHUNK;
  __syncthreads();
  if (t < NB) h[t] = lst[t];  // reuse as cursor
  __syncthreads();
  for (int i = t; i < CHUNK4; i += 512) {
    int4 s = src4[base4 + i];
    int4 d = dst4[base4 + i];
    float4 w = w4[base4 + i];
    int p;
    p = atomicAdd(&h[d.x >> 8], 1);
    ent[p] = make_int2(s.x | ((d.x & 255) << 17), __float_as_int(w.x));
    p = atomicAdd(&h[d.y >> 8], 1);
    ent[p] = make_int2(s.y | ((d.y & 255) << 17), __float_as_int(w.y));
    p = atomicAdd(&h[d.z >> 8], 1);
    ent[p] = make_int2(s.z | ((d.z & 255) << 17), __float_as_int(w.z));
    p = atomicAdd(&h[d.w >> 8], 1);
    ent[p] = make_int2(s.w | ((d.w & 255) << 17), __float_as_int(w.w));
  }
  __syncthreads();
  // coalesced output: consecutive i within a run -> consecutive global addrs
  for (int i = t; i < CHUNK; i += 512) {
    int lo = 0, hi = NB;  // largest b with lst[b] <= i
    while (hi - lo > 1) { int mid = (lo + hi) >> 1; if (lst[mid] <= i) lo = mid; else hi = mid; }
    staging[og[lo] + (i - lst[lo])] = ent[i];
  }
}

// ---- F: per-bucket CSR finalize, LDS sort + coalesced meta write ----
__global__ __launch_bounds__(256) void csr_finalize(
    const int* __restrict__ bbase, const int2* __restrict__ staging,
    int2* __restrict__ meta, int* __restrict__ rowptr) {
  __shared__ int2 ent[FCAP];  // 71.4 KB
  __shared__ int hist[256], ps[256], cur[256];
  int t = (int)threadIdx.x, b = (int)blockIdx.x;
  int bs = bbase[b], be = bbase[b + 1];
  int cnt = be - bs;
  hist[t] = 0;
  __syncthreads();
  for (int i = bs + t; i < be; i += 256) atomicAdd(&hist[staging[i].x >> 17], 1);
  __syncthreads();
  int v = hist[t];
  ps[t] = v;
  __syncthreads();
  for (int o = 1; o < 256; o <<= 1) {
    int a = (t >= o) ? ps[t - o] : 0;
    __syncthreads();
    ps[t] += a;
    __syncthreads();
  }
  int lexcl = ps[t] - v;
  int n = b * 256 + t;
  if (n < N_NODES) rowptr[n] = bs + lexcl;
  if (cnt <= FCAP) {
    cur[t] = lexcl;
    __syncthreads();
    for (int i = bs + t; i < be; i += 256) {
      int2 m = staging[i];
      int p = atomicAdd(&cur[m.x >> 17], 1);
      ent[p] = make_int2(m.x & 0x1FFFF, m.y);
    }
    __syncthreads();
    for (int i = t; i < cnt; i += 256) meta[bs + i] = ent[i];
  } else {  // fallback: scattered global writes (correctness guard)
    cur[t] = bs + lexcl;
    __syncthreads();
    for (int i = bs + t; i < be; i += 256) {
      int2 m = staging[i];
      int p = atomicAdd(&cur[m.x >> 17], 1);
      meta[p] = make_int2(m.x & 0x1FFFF, m.y);
    }
  }
}

// ---- G: gather (round-10 proven): bf16 operand, scalar metadata, 8-deep ----
template <bool FINAL>
__global__ __launch_bounds__(256) void gather_kernel(
    const int* __restrict__ rowptr, const int2* __restrict__ meta,
    const unsigned short* __restrict__ gsrc, const unsigned short* __restrict__ z16,
    const float* __restrict__ c, const float* __restrict__ cc,
    float* __restrict__ outf, unsigned short* __restrict__ out16) {
  int t = (int)threadIdx.x, lane = t & 63;
  int wid = (int)((blockIdx.x * blockDim.x + t) >> 6);
  int nw = (int)((gridDim.x * blockDim.x) >> 6);
  float cl = FINAL ? c[lane] : 0.f;
  float ccl = FINAL ? cc[lane] : 0.f;

  for (int n = wid; n < N_NODES; n += nw) {
    int lo = __builtin_amdgcn_readfirstlane(rowptr[n]);
    int hi = __builtin_amdgcn_readfirstlane(rowptr[n + 1]);
    float acc0 = 0.f, acc1 = 0.f, wsum = 0.f;
    int j = lo;
    for (; j + 8 <= hi; j += 8) {
      int2 m0 = meta[j + 0], m1 = meta[j + 1], m2 = meta[j + 2], m3 = meta[j + 3];
      int2 m4 = meta[j + 4], m5 = meta[j + 5], m6 = meta[j + 6], m7 = meta[j + 7];
      float v0 = bf2f(gsrc[((size_t)m0.x << 6) + lane]);
      float v1 = bf2f(gsrc[((size_t)m1.x << 6) + lane]);
      float v2 = bf2f(gsrc[((size_t)m2.x << 6) + lane]);
      float v3 = bf2f(gsrc[((size_t)m3.x << 6) + lane]);
      float v4 = bf2f(gsrc[((size_t)m4.x << 6) + lane]);
      float v5 = bf2f(gsrc[((size_t)m5.x << 6) + lane]);
      float v6 = bf2f(gsrc[((size_t)m6.x << 6) + lane]);
      float v7 = bf2f(gsrc[((size_t)m7.x << 6) + lane]);
      acc0 = fmaf(v0, __int_as_float(m0.y), acc0);
      acc1 = fmaf(v1, __int_as_float(m1.y), acc1);
      acc0 = fmaf(v2, __int_as_float(m2.y), acc0);
      acc1 = fmaf(v3, __int_as_float(m3.y), acc1);
      acc0 = fmaf(v4, __int_as_float(m4.y), acc0);
      acc1 = fmaf(v5, __int_as_float(m5.y), acc1);
      acc0 = fmaf(v6, __int_as_float(m6.y), acc0);
      acc1 = fmaf(v7, __int_as_float(m7.y), acc1);
      if (FINAL) {
        float wa = (__int_as_float(m0.y) + __int_as_float(m1.y)) +
                   (__int_as_float(m2.y) + __int_as_float(m3.y));
        float wb = (__int_as_float(m4.y) + __int_as_float(m5.y)) +
                   (__int_as_float(m6.y) + __int_as_float(m7.y));
        wsum += wa + wb;
      }
    }
    for (; j < hi; ++j) {
      int2 m = meta[j];
      acc0 = fmaf(bf2f(gsrc[((size_t)m.x << 6) + lane]), __int_as_float(m.y), acc0);
      if (FINAL) wsum += __int_as_float(m.y);
    }
    float acc = acc0 + acc1;
    size_t o = ((size_t)n << 6) + lane;
    if (FINAL) {
      float t1n = bf2f(gsrc[o]);  // gsrc == t1 here
      float zn = bf2f(z16[o]);
      outf[o] = 0.25f * acc + 0.5f * t1n + 0.25f * zn + 0.5f * wsum * cl + ccl;
    } else {
      out16[o] = f2bf(acc);
    }
  }
}

extern "C" void kernel_launch(void* const* d_in, const int* in_sizes, int n_in,
                              void* d_out, int out_size, void* d_ws, size_t ws_size,
                              hipStream_t stream) {
  const int* edge_index = (const int*)d_in[0];
  const int* src = edge_index;          // row 0
  const int* dst = edge_index + NUM_E;  // row 1
  const float* w = (const float*)d_in[1];
  const float* user_emb = (const float*)d_in[2];
  const float* item_emb = (const float*)d_in[3];
  const float* W1 = (const float*)d_in[4];
  const float* b1 = (const float*)d_in[5];
  const float* W2 = (const float*)d_in[6];
  const float* b2 = (const float*)d_in[7];
  float* out = (float*)d_out;

  // workspace layout (~64.5 MB)
  unsigned short* z16 = (unsigned short*)d_ws;          // N*D bf16 (12.8 MB)
  int2* staging = (int2*)(z16 + (size_t)N_NODES * D);   // E int2 (25.6 MB)
  unsigned short* t1_16 = (unsigned short*)staging;     // alias: staging dead after finalize
  int2* meta = staging + NUM_E;                         // E int2 (25.6 MB)
  int* rowptr = (int*)(meta + NUM_E);                   // N+1 (pad 100352)
  int* tot = rowptr + 100352;                           // NB (pad 392)
  int* bbase = tot + 392;                               // NB+1 (pad 392)
  int* gcursor = bbase + 392;                           // NB (pad 392)
  float* Mbuf = (float*)(gcursor + 392);                // 4096
  float* cbuf = Mbuf + 4096;                            // 64
  float* ccbuf = cbuf + 64;                             // 64

  hipMemsetAsync(tot, 0, NB * sizeof(int), stream);

  micro_kernel<<<1, 256, 0, stream>>>(W1, W2, b1, b2, Mbuf, cbuf, ccbuf);
  zmm_kernel<<<(N_NODES + 63) / 64, 256, 0, stream>>>(user_emb, item_emb, Mbuf, z16);

  p1_hist<<<PBLK, 256, 0, stream>>>((const int4*)dst, tot);
  p2_scan<<<1, 512, 0, stream>>>(tot, bbase, gcursor, rowptr);
  p3_part<<<PBLK, 512, 0, stream>>>((const int4*)src, (const int4*)dst,
                                    (const float4*)w, gcursor, staging);
  csr_finalize<<<NB, 256, 0, stream>>>(bbase, staging, meta, rowptr);

  // t1 = S @ z   (bf16 store; overwrites dead staging region)
  gather_kernel<false><<<2048, 256, 0, stream>>>(rowptr, meta, z16, z16, cbuf,
                                                 ccbuf, nullptr, t1_16);
  // out = 0.25*S@t1 + 0.5*t1 + 0.25*z + 0.5*dw*c + cc  (f32 output)
  gather_kernel<true><<<2048, 256, 0, stream>>>(rowptr, meta, t1_16, z16, cbuf,
                                                ccbuf, out, nullptr);
}

// Round 15
// 345.774 us; speedup vs baseline: 1.6792x; 1.1143x over previous
//
#include <hip/hip_runtime.h>

#define N_NODES 100000
#define NUM_U 50000
#define D 64
#define NUM_E 3200000
#define NB 391                  // buckets of 256 dst nodes
#define P3B 500                 // partition blocks
#define ZMB 1563                // zmm blocks (ceil(100000/64))
#define CHUNK (NUM_E / P3B)     // 6400 edges per partition block
#define CHUNK4 (CHUNK / 4)      // 1600
#define FCAP 8928               // per-bucket capacity (mean+8sigma) & LDS cap
#define NBF (NB * FCAP)         // 3,490,848 staged entries
#define K1_LDS 70744            // p3-role LDS bytes (ent+bkt+h+lst+og+ps)

__device__ __forceinline__ float bf2f(unsigned short u) {
  return __uint_as_float((unsigned)u << 16);
}
__device__ __forceinline__ unsigned short f2bf(float f) {
  unsigned u = __float_as_uint(f);
  u += 0x7FFF + ((u >> 16) & 1);  // RNE
  return (unsigned short)(u >> 16);
}

// ---- K0: micro (M = (W2@W1)^T, c = b1@W2^T, cc = 0.5c+b2) + zero cursors ----
__global__ __launch_bounds__(256) void micro_kernel(
    const float* __restrict__ W1, const float* __restrict__ W2,
    const float* __restrict__ b1, const float* __restrict__ b2,
    float* __restrict__ M, float* __restrict__ c, float* __restrict__ cc,
    int* __restrict__ cur) {
  __shared__ float w1[64][65], w2[64][65];
  int t = (int)threadIdx.x;
  for (int i = t; i < NB; i += 256) cur[i] = 0;
  for (int i = t; i < 4096; i += 256) { w1[i >> 6][i & 63] = W1[i]; w2[i >> 6][i & 63] = W2[i]; }
  __syncthreads();
  for (int i = t; i < 4096; i += 256) {
    int k = i >> 6, j = i & 63;
    float s = 0.f;
#pragma unroll
    for (int tt = 0; tt < 64; ++tt) s = fmaf(w2[j][tt], w1[tt][k], s);
    M[i] = s;  // M[k][j]
  }
  if (t < 64) {
    float s = 0.f;
#pragma unroll
    for (int tt = 0; tt < 64; ++tt) s = fmaf(b1[tt], w2[t][tt], s);
    c[t] = s;
    cc[t] = 0.5f * s + b2[t];
  }
}

// ---- K1: fused {p3 LDS radix-partition (blocks 0..P3B-1)} + {zmm (rest)} ----
__global__ __launch_bounds__(512) void k1_kernel(
    const int4* __restrict__ src4, const int4* __restrict__ dst4,
    const float4* __restrict__ w4, int* __restrict__ cur,
    int2* __restrict__ staging, const float* __restrict__ xu,
    const float* __restrict__ xi, const float* __restrict__ M,
    unsigned short* __restrict__ z16) {
  __shared__ long long smem8[K1_LDS / 8];
  char* smem = (char*)smem8;
  int t = (int)threadIdx.x, blk = (int)blockIdx.x;

  if (blk < P3B) {
    // ---- p3 role: partition chunk into per-bucket runs, coalesced writes ----
    int2* ent = (int2*)smem;                              // 51200 B
    unsigned short* bkt = (unsigned short*)(smem + 51200);  // 12800 B
    int* h = (int*)(smem + 64000);                        // NB
    int* lst = (int*)(smem + 65564);                      // NB+1
    int* og = (int*)(smem + 67132);                       // NB
    int* ps = (int*)(smem + 68696);                       // 512
    for (int i = t; i < NB; i += 512) h[i] = 0;
    __syncthreads();
    int base4 = blk * CHUNK4;
    for (int i = t; i < CHUNK4; i += 512) {
      int4 d = dst4[base4 + i];
      atomicAdd(&h[d.x >> 8], 1); atomicAdd(&h[d.y >> 8], 1);
      atomicAdd(&h[d.z >> 8], 1); atomicAdd(&h[d.w >> 8], 1);
    }
    __syncthreads();
    int v = (t < NB) ? h[t] : 0;
    ps[t] = v;
    __syncthreads();
    for (int o = 1; o < 512; o <<= 1) {
      int a = (t >= o) ? ps[t - o] : 0;
      __syncthreads();
      ps[t] += a;
      __syncthreads();
    }
    if (t < NB) {
      lst[t] = ps[t] - v;
      og[t] = v ? (t * FCAP + atomicAdd(&cur[t], v)) : 0;
    }
    if (t == 0) lst[NB] = CHUNK;
    __syncthreads();
    if (t < NB) h[t] = lst[t];  // reuse as cursor
    __syncthreads();
    for (int i = t; i < CHUNK4; i += 512) {
      int4 s = src4[base4 + i];
      int4 d = dst4[base4 + i];
      float4 w = w4[base4 + i];
      int p;
      p = atomicAdd(&h[d.x >> 8], 1);
      ent[p] = make_int2(s.x | ((d.x & 255) << 17), __float_as_int(w.x));
      bkt[p] = (unsigned short)(d.x >> 8);
      p = atomicAdd(&h[d.y >> 8], 1);
      ent[p] = make_int2(s.y | ((d.y & 255) << 17), __float_as_int(w.y));
      bkt[p] = (unsigned short)(d.y >> 8);
      p = atomicAdd(&h[d.z >> 8], 1);
      ent[p] = make_int2(s.z | ((d.z & 255) << 17), __float_as_int(w.z));
      bkt[p] = (unsigned short)(d.z >> 8);
      p = atomicAdd(&h[d.w >> 8], 1);
      ent[p] = make_int2(s.w | ((d.w & 255) << 17), __float_as_int(w.w));
      bkt[p] = (unsigned short)(d.w >> 8);
    }
    __syncthreads();
    for (int i = t; i < CHUNK; i += 512) {
      int b = bkt[i];
      int gi = og[b] + (i - lst[b]);
      if (gi < (b + 1) * FCAP) staging[gi] = ent[i];  // defensive overflow clamp
    }
  } else {
    // ---- zmm role: z = x @ M, stored bf16 (64 nodes per block) ----
    float* Mt = (float*)smem;            // 64*65 f32 (Mt[j*65+k] = M[k][j])
    float* U = (float*)(smem + 16640);   // 64*65 f32
    for (int i = t; i < 4096; i += 512) Mt[(i & 63) * 65 + (i >> 6)] = M[i];
    int lane = t & 63, row = t >> 6;  // row 0..7
    int n0 = (blk - P3B) * 64;
#pragma unroll
    for (int i = 0; i < 8; ++i) {
      int nl = row + 8 * i, n = n0 + nl;
      if (n < N_NODES) {
        const float* xr = (n < NUM_U) ? (xu + (size_t)n * D) : (xi + (size_t)(n - NUM_U) * D);
        U[nl * 65 + lane] = xr[lane];
      }
    }
    __syncthreads();
#pragma unroll
    for (int i = 0; i < 8; ++i) {
      int nl = row + 8 * i, n = n0 + nl;
      if (n >= N_NODES) continue;
      float s = 0.f;
#pragma unroll
      for (int k = 0; k < 64; ++k) s = fmaf(U[nl * 65 + k], Mt[lane * 65 + k], s);
      z16[(size_t)n * D + lane] = f2bf(s);
    }
  }
}

// ---- K2: per-bucket finalize: node-sort in LDS, coalesced meta, rowse ----
__global__ __launch_bounds__(512) void fin_kernel(
    const int* __restrict__ cur, const int2* __restrict__ staging,
    int2* __restrict__ meta, int2* __restrict__ rowse) {
  __shared__ int2 ent[FCAP];  // 71.4 KB
  __shared__ int hist[256], ps[256], cl[256];
  int t = (int)threadIdx.x, b = (int)blockIdx.x;
  int bs = b * FCAP;
  int cnt = cur[b];
  if (cnt > FCAP) cnt = FCAP;
  int be = bs + cnt;
  if (t < 256) hist[t] = 0;
  __syncthreads();
  for (int i = bs + t; i < be; i += 512) atomicAdd(&hist[staging[i].x >> 17], 1);
  __syncthreads();
  int v = (t < 256) ? hist[t] : 0;
  if (t < 256) ps[t] = v;
  __syncthreads();
  for (int o = 1; o < 256; o <<= 1) {
    int a = (t >= o && t < 256) ? ps[t - o] : 0;
    __syncthreads();
    if (t < 256) ps[t] += a;
    __syncthreads();
  }
  int lexcl = (t < 256) ? (ps[t] - v) : 0;
  int n = b * 256 + t;
  if (t < 256 && n < N_NODES)
    rowse[n] = make_int2(bs + lexcl, bs + lexcl + v);
  if (t < 256) cl[t] = lexcl;
  __syncthreads();
  for (int i = bs + t; i < be; i += 512) {
    int2 m = staging[i];
    int p = atomicAdd(&cl[m.x >> 17], 1);
    ent[p] = make_int2(m.x & 0x1FFFF, m.y);
  }
  __syncthreads();
  for (int i = t; i < cnt; i += 512) meta[bs + i] = ent[i];
}

// ---- G: gather (round-10 proven): bf16 operand, scalar metadata, 8-deep ----
template <bool FINAL>
__global__ __launch_bounds__(256) void gather_kernel(
    const int2* __restrict__ rowse, const int2* __restrict__ meta,
    const unsigned short* __restrict__ gsrc, const unsigned short* __restrict__ z16,
    const float* __restrict__ c, const float* __restrict__ cc,
    float* __restrict__ outf, unsigned short* __restrict__ out16) {
  int t = (int)threadIdx.x, lane = t & 63;
  int wid = (int)((blockIdx.x * blockDim.x + t) >> 6);
  int nw = (int)((gridDim.x * blockDim.x) >> 6);
  float cl = FINAL ? c[lane] : 0.f;
  float ccl = FINAL ? cc[lane] : 0.f;

  for (int n = wid; n < N_NODES; n += nw) {
    int2 se = rowse[n];
    int lo = __builtin_amdgcn_readfirstlane(se.x);
    int hi = __builtin_amdgcn_readfirstlane(se.y);
    float acc0 = 0.f, acc1 = 0.f, wsum = 0.f;
    int j = lo;
    for (; j + 8 <= hi; j += 8) {
      int2 m0 = meta[j + 0], m1 = meta[j + 1], m2 = meta[j + 2], m3 = meta[j + 3];
      int2 m4 = meta[j + 4], m5 = meta[j + 5], m6 = meta[j + 6], m7 = meta[j + 7];
      float v0 = bf2f(gsrc[((size_t)m0.x << 6) + lane]);
      float v1 = bf2f(gsrc[((size_t)m1.x << 6) + lane]);
      float v2 = bf2f(gsrc[((size_t)m2.x << 6) + lane]);
      float v3 = bf2f(gsrc[((size_t)m3.x << 6) + lane]);
      float v4 = bf2f(gsrc[((size_t)m4.x << 6) + lane]);
      float v5 = bf2f(gsrc[((size_t)m5.x << 6) + lane]);
      float v6 = bf2f(gsrc[((size_t)m6.x << 6) + lane]);
      float v7 = bf2f(gsrc[((size_t)m7.x << 6) + lane]);
      acc0 = fmaf(v0, __int_as_float(m0.y), acc0);
      acc1 = fmaf(v1, __int_as_float(m1.y), acc1);
      acc0 = fmaf(v2, __int_as_float(m2.y), acc0);
      acc1 = fmaf(v3, __int_as_float(m3.y), acc1);
      acc0 = fmaf(v4, __int_as_float(m4.y), acc0);
      acc1 = fmaf(v5, __int_as_float(m5.y), acc1);
      acc0 = fmaf(v6, __int_as_float(m6.y), acc0);
      acc1 = fmaf(v7, __int_as_float(m7.y), acc1);
      if (FINAL) {
        float wa = (__int_as_float(m0.y) + __int_as_float(m1.y)) +
                   (__int_as_float(m2.y) + __int_as_float(m3.y));
        float wb = (__int_as_float(m4.y) + __int_as_float(m5.y)) +
                   (__int_as_float(m6.y) + __int_as_float(m7.y));
        wsum += wa + wb;
      }
    }
    for (; j < hi; ++j) {
      int2 m = meta[j];
      acc0 = fmaf(bf2f(gsrc[((size_t)m.x << 6) + lane]), __int_as_float(m.y), acc0);
      if (FINAL) wsum += __int_as_float(m.y);
    }
    float acc = acc0 + acc1;
    size_t o = ((size_t)n << 6) + lane;
    if (FINAL) {
      float t1n = bf2f(gsrc[o]);  // gsrc == t1 here
      float zn = bf2f(z16[o]);
      outf[o] = 0.25f * acc + 0.5f * t1n + 0.25f * zn + 0.5f * wsum * cl + ccl;
    } else {
      out16[o] = f2bf(acc);
    }
  }
}

extern "C" void kernel_launch(void* const* d_in, const int* in_sizes, int n_in,
                              void* d_out, int out_size, void* d_ws, size_t ws_size,
                              hipStream_t stream) {
  const int* edge_index = (const int*)d_in[0];
  const float* w = (const float*)d_in[1];
  const float* user_emb = (const float*)d_in[2];
  const float* item_emb = (const float*)d_in[3];
  const float* W1 = (const float*)d_in[4];
  const float* b1 = (const float*)d_in[5];
  const float* W2 = (const float*)d_in[6];
  const float* b2 = (const float*)d_in[7];
  float* out = (float*)d_out;

  // workspace layout (~69.5 MB)
  unsigned short* z16 = (unsigned short*)d_ws;          // N*D bf16 (12.8 MB)
  int2* staging = (int2*)(z16 + (size_t)N_NODES * D);   // NBF int2 (27.9 MB)
  unsigned short* t1_16 = (unsigned short*)staging;     // alias: staging dead after fin
  int2* meta = staging + NBF;                           // NBF int2 (27.9 MB)
  int2* rowse = meta + NBF;                             // N int2 (0.8 MB)
  int* cur = (int*)(rowse + N_NODES);                   // NB (pad 392)
  float* Mbuf = (float*)(cur + 392);                    // 4096
  float* cbuf = Mbuf + 4096;                            // 64
  float* ccbuf = cbuf + 64;                             // 64

  const int4* src4 = (const int4*)edge_index;
  const int4* dst4 = (const int4*)(edge_index + NUM_E);
  const float4* w4 = (const float4*)w;

  micro_kernel<<<1, 256, 0, stream>>>(W1, W2, b1, b2, Mbuf, cbuf, ccbuf, cur);
  k1_kernel<<<P3B + ZMB, 512, 0, stream>>>(src4, dst4, w4, cur, staging,
                                           user_emb, item_emb, Mbuf, z16);
  fin_kernel<<<NB, 512, 0, stream>>>(cur, staging, meta, rowse);

  // t1 = S @ z   (bf16 store; overwrites dead staging region)
  gather_kernel<false><<<2048, 256, 0, stream>>>(rowse, meta, z16, z16, cbuf,
                                                 ccbuf, nullptr, t1_16);
  // out = 0.25*S@t1 + 0.5*t1 + 0.25*z + 0.5*dw*c + cc  (f32 output)
  gather_kernel<true><<<2048, 256, 0, stream>>>(rowse, meta, t1_16, z16, cbuf,
                                                ccbuf, out, nullptr);
}